// Round 5
// baseline (87.292 us; speedup 1.0000x reference)
//
#include <hip/hip_runtime.h>
#include <math.h>

// DynamicTrackHead — R5: occupancy-first K1.
// K1: grid (n_inst, 2, 30), block 64 = one wave. 2 threads per pooled pixel
//     (tid>>5 = qy half), 32 pixels/block. conv0(relu,pool2)+conv1(relu,
//     partial pool) in registers; qy-pool via __shfl_xor(32); conv2 fully in
//     registers (32 ch/thread, SGPR weights); 5-stage butterfly sum over the
//     32 pixels; lanes 0/32 write 64 partials. No LDS, no barrier.
//     __launch_bounds__(64,8) forces VGPR<=64 -> 8 waves/SIMD eligible.
// K2: grid (n_inst, 2), block 128. Sum 30 partials -> mean -> MLP -> out.
// params/instance = 736 floats: w0[8][10]@0, w1[8][8]@80, w2[64][8]@144,
// b0@656, b1@664, b2@672.

#define H_IN 96
#define W_IN 160
#define HW_IN (H_IN * W_IN)
#define PW 40            // W_IN / 4
#define PH 24            // H_IN / 4
#define NPIX (PH * PW)   // 960 pooled-twice pixels
#define NCHUNK 30        // K1 blocks per (inst,head)
#define CPIX 32          // pixels per K1 block
#define NPARAM 736
#define OW0 0
#define OW1 80
#define OW2 144
#define OB0 656
#define OB1 664
#define OB2 672

#define SELU_SCALE 1.0507009873554805f
#define SELU_ALPHA 1.6732632423543772f

// ---------------------------------------------------------------------------
// K1: conv tower + partial spatial sum. One wave per block, no LDS.
// ---------------------------------------------------------------------------
__global__ __launch_bounds__(64, 8) void track_head_conv(
    const float* __restrict__ mask_feats,
    const float* __restrict__ pmain,
    const float* __restrict__ pside,
    const int*   __restrict__ im_inds,
    const float* __restrict__ inst_loc,
    const float* __restrict__ offset_pred,
    const int*   __restrict__ fpn_levels,
    const int*   __restrict__ stride_ptr,
    float*       __restrict__ ws_part)      // [n_inst][2][NCHUNK][64]
{
    const int inst  = blockIdx.x;
    const int head  = blockIdx.y;
    const int chunk = blockIdx.z;
    const int tid   = threadIdx.x;          // 0..63
    const int pix   = tid & 31;             // pixel within chunk
    const int qy    = tid >> 5;             // which pool-2 row half

    const float* __restrict__ P = (head ? pside : pmain) + (size_t)inst * NPARAM;

    const int S  = stride_ptr[0];
    const int S2 = S / 2;
    float lx = inst_loc[inst * 2 + 0];
    float ly = inst_loc[inst * 2 + 1];
    if (head) {
        lx += offset_pred[inst * 2 + 0] * 128.0f;
        ly += offset_pred[inst * 2 + 1] * 128.0f;
    }
    const float inv_soi = 1.0f / (float)(64 << fpn_levels[inst]);
    const float* __restrict__ feat =
        mask_feats + (size_t)im_inds[inst] * 8 * HW_IN;

    const int p   = chunk * CPIX + pix;     // 0..959
    const int py  = p / PW;
    const int px  = p - py * PW;
    const int ix0 = px * 4;
    const int iyb = py * 4 + qy * 2;        // this thread's two input rows

    // ---- conv0 (relu folded into max), accumulate quadrant maxes ----
    float m0a[8], m0b[8];                   // pool-1 pixels (qy,qx=0/1), >=0
    #pragma unroll
    for (int o = 0; o < 8; o++) { m0a[o] = 0.0f; m0b[o] = 0.0f; }

    #pragma unroll
    for (int sy = 0; sy < 2; sy++) {
        const int iy = iyb + sy;
        const float x1 = (ly - (float)(iy * S + S2)) * inv_soi;
        const float* rowp = feat + iy * W_IN + ix0;
        const float4 f0 = *(const float4*)(rowp + 0 * HW_IN);
        const float4 f1 = *(const float4*)(rowp + 1 * HW_IN);
        const float4 f2 = *(const float4*)(rowp + 2 * HW_IN);
        const float4 f3 = *(const float4*)(rowp + 3 * HW_IN);
        const float4 f4 = *(const float4*)(rowp + 4 * HW_IN);
        const float4 f5 = *(const float4*)(rowp + 5 * HW_IN);
        const float4 f6 = *(const float4*)(rowp + 6 * HW_IN);
        const float4 f7 = *(const float4*)(rowp + 7 * HW_IN);

#define L0_PIX(JJ, COMP, M0ARR)                                                 \
        {                                                                       \
            const float x0 = (lx - (float)((ix0 + JJ) * S + S2)) * inv_soi;     \
            _Pragma("unroll")                                                   \
            for (int o = 0; o < 8; o++) {                                       \
                const float* w0r = P + OW0 + o * 10;                            \
                float a = P[OB0 + o] + w0r[0] * x0 + w0r[1] * x1                \
                        + w0r[2] * f0.COMP + w0r[3] * f1.COMP                   \
                        + w0r[4] * f2.COMP + w0r[5] * f3.COMP                   \
                        + w0r[6] * f4.COMP + w0r[7] * f5.COMP                   \
                        + w0r[8] * f6.COMP + w0r[9] * f7.COMP;                  \
                M0ARR[o] = fmaxf(M0ARR[o], a);                                  \
            }                                                                   \
        }
        L0_PIX(0, x, m0a)
        L0_PIX(1, y, m0a)
        L0_PIX(2, z, m0b)
        L0_PIX(3, w, m0b)
#undef L0_PIX
    }

    // ---- conv1 (relu) + pool over qx (local) and qy (cross-lane) ----
    float m1[8];
    #pragma unroll
    for (int o = 0; o < 8; o++) {
        float a = P[OB1 + o];
        float b = a;
        #pragma unroll
        for (int c = 0; c < 8; c++) {
            const float w = P[OW1 + o * 8 + c];
            a += w * m0a[c];
            b += w * m0b[c];
        }
        const float h = fmaxf(fmaxf(a, b), 0.0f);
        m1[o] = fmaxf(h, __shfl_xor(h, 32, 64));   // pool across qy halves
    }

    // ---- conv2 (relu), 32 output channels per thread, in registers ----
    const int obase = qy * 32;
    float acc[32];
    #pragma unroll
    for (int k = 0; k < 32; k++) {
        const int o = obase + k;
        const float* w2r = P + OW2 + o * 8;
        float a = P[OB2 + o]
                + w2r[0] * m1[0] + w2r[1] * m1[1] + w2r[2] * m1[2]
                + w2r[3] * m1[3] + w2r[4] * m1[4] + w2r[5] * m1[5]
                + w2r[6] * m1[6] + w2r[7] * m1[7];
        acc[k] = fmaxf(a, 0.0f);
    }

    // ---- butterfly sum over the 32 pixels (lanes within each half) ----
    #pragma unroll
    for (int m = 1; m <= 16; m <<= 1) {
        #pragma unroll
        for (int k = 0; k < 32; k++)
            acc[k] += __shfl_xor(acc[k], m, 64);
    }

    if (pix == 0) {   // lanes 0 and 32: write 32 channels each
        float* base = ws_part +
            (((size_t)inst * 2 + head) * NCHUNK + chunk) * 64 + obase;
        #pragma unroll
        for (int k8 = 0; k8 < 8; k8++) {
            ((float4*)base)[k8] = make_float4(acc[k8 * 4 + 0], acc[k8 * 4 + 1],
                                              acc[k8 * 4 + 2], acc[k8 * 4 + 3]);
        }
    }
}

// ---------------------------------------------------------------------------
// K2: combine partials -> mean -> MLP (fc1 -> LN -> SELU -> fc2) -> logits
// ---------------------------------------------------------------------------
__global__ __launch_bounds__(128) void track_head_mlp(
    const float* __restrict__ ws_part,
    const float* __restrict__ mw1, const float* __restrict__ mb1,
    const float* __restrict__ mg,  const float* __restrict__ mbeta,
    const float* __restrict__ mw2, const float* __restrict__ mb2,
    const float* __restrict__ sw1, const float* __restrict__ sb1,
    const float* __restrict__ sg,  const float* __restrict__ sbeta,
    const float* __restrict__ sw2, const float* __restrict__ sb2,
    float*       __restrict__ out,
    int n_inst)
{
    const int inst = blockIdx.x;
    const int head = blockIdx.y;
    const int tid  = threadIdx.x;
    const int lane = tid & 63;
    const int wid  = tid >> 6;

    __shared__ __align__(16) float s_x[64];
    __shared__ __align__(16) float s_h[128];
    __shared__ float s_r[4];

    if (tid < 64) {
        const float* base = ws_part + ((size_t)inst * 2 + head) * NCHUNK * 64 + tid;
        float xm = 0.0f;
        #pragma unroll
        for (int q = 0; q < NCHUNK; q++) xm += base[q * 64];
        s_x[tid] = xm * (1.0f / (float)NPIX);
    }
    __syncthreads();

    const float* __restrict__ w1h = head ? sw1 : mw1;
    const float* __restrict__ b1h = head ? sb1 : mb1;
    const float* __restrict__ gh  = head ? sg  : mg;
    const float* __restrict__ bth = head ? sbeta : mbeta;
    const float* __restrict__ w2h = head ? sw2 : mw2;
    const float* __restrict__ b2h = head ? sb2 : mb2;

    float hval = 0.0f, dval = 0.0f;
    {
        const float* wr = w1h + tid * 64;
        float a = b1h[tid];
        #pragma unroll
        for (int k = 0; k < 16; k++) {
            const float4 wv = *(const float4*)(wr + k * 4);
            const float4 xv = *(const float4*)(&s_x[k * 4]);
            a += wv.x * xv.x + wv.y * xv.y + wv.z * xv.z + wv.w * xv.w;
        }
        hval = a;
    }
    {
        float s = hval;
        #pragma unroll
        for (int m = 32; m >= 1; m >>= 1) s += __shfl_xor(s, m, 64);
        if (lane == 0) s_r[wid] = s;
    }
    __syncthreads();
    const float mu = (s_r[0] + s_r[1]) * (1.0f / 128.0f);
    dval = hval - mu;
    {
        float s = dval * dval;
        #pragma unroll
        for (int m = 32; m >= 1; m >>= 1) s += __shfl_xor(s, m, 64);
        if (lane == 0) s_r[wid + 2] = s;
    }
    __syncthreads();
    const float var = (s_r[2] + s_r[3]) * (1.0f / 128.0f);

    {
        const float hn = dval * (1.0f / sqrtf(var + 1e-5f)) * gh[tid] + bth[tid];
        const float sv = (hn > 0.0f)
                           ? SELU_SCALE * hn
                           : SELU_SCALE * SELU_ALPHA * (expf(hn) - 1.0f);
        s_h[tid] = sv;
    }
    __syncthreads();

    if (tid < 64) {
        const float* wr = w2h + tid * 128;
        float a = b2h[tid];
        #pragma unroll
        for (int k = 0; k < 32; k++) {
            const float4 wv = *(const float4*)(wr + k * 4);
            const float4 hv = *(const float4*)(&s_h[k * 4]);
            a += wv.x * hv.x + wv.y * hv.y + wv.z * hv.z + wv.w * hv.w;
        }
        out[(size_t)head * (size_t)n_inst * 64 + (size_t)inst * 64 + tid] = a;
    }
}

extern "C" void kernel_launch(void* const* d_in, const int* in_sizes, int n_in,
                              void* d_out, int out_size, void* d_ws, size_t ws_size,
                              hipStream_t stream) {
    const float* mask_feats  = (const float*)d_in[0];
    const float* pmain       = (const float*)d_in[1];
    const float* pside       = (const float*)d_in[2];
    const int*   im_inds     = (const int*)  d_in[3];
    const float* inst_loc    = (const float*)d_in[4];
    const float* offset_pred = (const float*)d_in[5];
    const int*   fpn_levels  = (const int*)  d_in[6];
    const float* mw1   = (const float*)d_in[7];
    const float* mb1   = (const float*)d_in[8];
    const float* mg    = (const float*)d_in[9];
    const float* mbeta = (const float*)d_in[10];
    const float* mw2   = (const float*)d_in[11];
    const float* mb2   = (const float*)d_in[12];
    const float* sw1   = (const float*)d_in[13];
    const float* sb1   = (const float*)d_in[14];
    const float* sg    = (const float*)d_in[15];
    const float* sbeta = (const float*)d_in[16];
    const float* sw2   = (const float*)d_in[17];
    const float* sb2   = (const float*)d_in[18];
    const int*   strid = (const int*)  d_in[19];
    float* out = (float*)d_out;

    const int n_inst = in_sizes[3];   // im_inds length
    float* ws_part = (float*)d_ws;    // n_inst*2*NCHUNK*64 floats ~= 2 MB

    dim3 g1(n_inst, 2, NCHUNK);
    track_head_conv<<<g1, 64, 0, stream>>>(
        mask_feats, pmain, pside, im_inds, inst_loc, offset_pred, fpn_levels,
        strid, ws_part);

    dim3 g2(n_inst, 2);
    track_head_mlp<<<g2, 128, 0, stream>>>(
        ws_part,
        mw1, mb1, mg, mbeta, mw2, mb2,
        sw1, sb1, sg, sbeta, sw2, sb2,
        out, n_inst);
}

// Round 6
// 43.083 us; speedup vs baseline: 2.0261x; 2.0261x over previous
//
#include <hip/hip_runtime.h>
#include <math.h>

// DynamicTrackHead — R6: R5's occupancy structure + R4's LDS conv2 (no spills).
// K1: grid (n_inst, 2, 30), block 64 = one wave. 2 threads per pooled pixel
//     (tid>>5 = qy half), 32 pixels/block. conv0(relu,pool2x)+conv1(relu) in
//     registers; qy-pool via __shfl_xor(32); m1 staged to 1 KB LDS; conv2 with
//     one output channel per thread (broadcast LDS reads, no conflicts);
//     64 partial sums to d_ws. VGPR target <=64 -> 8 waves/SIMD bucket.
//     Grid gives 30 one-wave blocks per CU.
// K2: grid (n_inst, 2), block 128. Sum 30 partials -> mean -> MLP -> out.
// params/instance = 736 floats: w0[8][10]@0, w1[8][8]@80, w2[64][8]@144,
// b0@656, b1@664, b2@672.

#define H_IN 96
#define W_IN 160
#define HW_IN (H_IN * W_IN)
#define PW 40            // W_IN / 4
#define PH 24            // H_IN / 4
#define NPIX (PH * PW)   // 960 pooled-twice pixels
#define NCHUNK 30        // K1 blocks per (inst,head)
#define CPIX 32          // pooled pixels per K1 block
#define NPARAM 736
#define OW0 0
#define OW1 80
#define OW2 144
#define OB0 656
#define OB1 664
#define OB2 672

#define SELU_SCALE 1.0507009873554805f
#define SELU_ALPHA 1.6732632423543772f

// ---------------------------------------------------------------------------
// K1: conv tower + partial spatial sum. One wave per block.
// ---------------------------------------------------------------------------
__global__ __launch_bounds__(64, 8) void track_head_conv(
    const float* __restrict__ mask_feats,
    const float* __restrict__ pmain,
    const float* __restrict__ pside,
    const int*   __restrict__ im_inds,
    const float* __restrict__ inst_loc,
    const float* __restrict__ offset_pred,
    const int*   __restrict__ fpn_levels,
    const int*   __restrict__ stride_ptr,
    float*       __restrict__ ws_part)      // [n_inst][2][NCHUNK][64]
{
    const int inst  = blockIdx.x;
    const int head  = blockIdx.y;
    const int chunk = blockIdx.z;
    const int tid   = threadIdx.x;          // 0..63
    const int pix   = tid & 31;             // pixel within chunk
    const int qy    = tid >> 5;             // which pool-2 row half

    __shared__ __align__(16) float s_m1[CPIX][8];   // 1 KB

    const float* __restrict__ P = (head ? pside : pmain) + (size_t)inst * NPARAM;

    const int S  = stride_ptr[0];
    const int S2 = S / 2;
    float lx = inst_loc[inst * 2 + 0];
    float ly = inst_loc[inst * 2 + 1];
    if (head) {
        lx += offset_pred[inst * 2 + 0] * 128.0f;
        ly += offset_pred[inst * 2 + 1] * 128.0f;
    }
    const float inv_soi = 1.0f / (float)(64 << fpn_levels[inst]);
    const float* __restrict__ feat =
        mask_feats + (size_t)im_inds[inst] * 8 * HW_IN;

    const int p   = chunk * CPIX + pix;     // 0..959
    const int py  = p / PW;
    const int px  = p - py * PW;
    const int ix0 = px * 4;
    const int iyb = py * 4 + qy * 2;        // this thread's two input rows

    // ---- conv0 (relu folded into max), accumulate quadrant maxes ----
    float m0a[8], m0b[8];                   // pool-1 pixels (qy,qx=0/1), >=0
    #pragma unroll
    for (int o = 0; o < 8; o++) { m0a[o] = 0.0f; m0b[o] = 0.0f; }

    #pragma unroll
    for (int sy = 0; sy < 2; sy++) {
        const int iy = iyb + sy;
        const float x1 = (ly - (float)(iy * S + S2)) * inv_soi;
        const float* rowp = feat + iy * W_IN + ix0;
        const float4 f0 = *(const float4*)(rowp + 0 * HW_IN);
        const float4 f1 = *(const float4*)(rowp + 1 * HW_IN);
        const float4 f2 = *(const float4*)(rowp + 2 * HW_IN);
        const float4 f3 = *(const float4*)(rowp + 3 * HW_IN);
        const float4 f4 = *(const float4*)(rowp + 4 * HW_IN);
        const float4 f5 = *(const float4*)(rowp + 5 * HW_IN);
        const float4 f6 = *(const float4*)(rowp + 6 * HW_IN);
        const float4 f7 = *(const float4*)(rowp + 7 * HW_IN);

#define L0_PIX(JJ, COMP, M0ARR)                                                 \
        {                                                                       \
            const float x0 = (lx - (float)((ix0 + JJ) * S + S2)) * inv_soi;     \
            _Pragma("unroll")                                                   \
            for (int o = 0; o < 8; o++) {                                       \
                const float* w0r = P + OW0 + o * 10;                            \
                float a = P[OB0 + o] + w0r[0] * x0 + w0r[1] * x1                \
                        + w0r[2] * f0.COMP + w0r[3] * f1.COMP                   \
                        + w0r[4] * f2.COMP + w0r[5] * f3.COMP                   \
                        + w0r[6] * f4.COMP + w0r[7] * f5.COMP                   \
                        + w0r[8] * f6.COMP + w0r[9] * f7.COMP;                  \
                M0ARR[o] = fmaxf(M0ARR[o], a);                                  \
            }                                                                   \
        }
        L0_PIX(0, x, m0a)
        L0_PIX(1, y, m0a)
        L0_PIX(2, z, m0b)
        L0_PIX(3, w, m0b)
#undef L0_PIX
    }

    // ---- conv1 (relu) + pool over qx (local) and qy (cross-lane) ----
    float m1[8];
    #pragma unroll
    for (int o = 0; o < 8; o++) {
        float a = P[OB1 + o];
        float b = a;
        #pragma unroll
        for (int c = 0; c < 8; c++) {
            const float w = P[OW1 + o * 8 + c];
            a += w * m0a[c];
            b += w * m0b[c];
        }
        const float h = fmaxf(fmaxf(a, b), 0.0f);
        m1[o] = fmaxf(h, __shfl_xor(h, 32, 64));   // pool across qy halves
    }

    // ---- stage m1 to LDS (lanes 0..31 hold the pooled values too) ----
    if (qy == 0) {
        float4* dst = (float4*)&s_m1[pix][0];
        dst[0] = make_float4(m1[0], m1[1], m1[2], m1[3]);
        dst[1] = make_float4(m1[4], m1[5], m1[6], m1[7]);
    }
    __syncthreads();

    // ---- conv2 (relu): one output channel per thread, broadcast LDS reads --
    {
        const int o = tid;                    // output channel 0..63
        const float4 wa = *(const float4*)(P + OW2 + o * 8);
        const float4 wb = *(const float4*)(P + OW2 + o * 8 + 4);
        const float  bo = P[OB2 + o];
        float accum = 0.0f;
        #pragma unroll 4
        for (int p2 = 0; p2 < CPIX; p2++) {
            const float4 va = *(const float4*)&s_m1[p2][0];   // broadcast read
            const float4 vb = *(const float4*)&s_m1[p2][4];
            float a = bo + wa.x * va.x + wa.y * va.y + wa.z * va.z + wa.w * va.w
                         + wb.x * vb.x + wb.y * vb.y + wb.z * vb.z + wb.w * vb.w;
            accum += fmaxf(a, 0.0f);
        }
        ws_part[(((size_t)inst * 2 + head) * NCHUNK + chunk) * 64 + o] = accum;
    }
}

// ---------------------------------------------------------------------------
// K2: combine partials -> mean -> MLP (fc1 -> LN -> SELU -> fc2) -> logits
// ---------------------------------------------------------------------------
__global__ __launch_bounds__(128) void track_head_mlp(
    const float* __restrict__ ws_part,
    const float* __restrict__ mw1, const float* __restrict__ mb1,
    const float* __restrict__ mg,  const float* __restrict__ mbeta,
    const float* __restrict__ mw2, const float* __restrict__ mb2,
    const float* __restrict__ sw1, const float* __restrict__ sb1,
    const float* __restrict__ sg,  const float* __restrict__ sbeta,
    const float* __restrict__ sw2, const float* __restrict__ sb2,
    float*       __restrict__ out,
    int n_inst)
{
    const int inst = blockIdx.x;
    const int head = blockIdx.y;
    const int tid  = threadIdx.x;
    const int lane = tid & 63;
    const int wid  = tid >> 6;

    __shared__ __align__(16) float s_x[64];
    __shared__ __align__(16) float s_h[128];
    __shared__ float s_r[4];

    if (tid < 64) {
        const float* base = ws_part + ((size_t)inst * 2 + head) * NCHUNK * 64 + tid;
        float xm = 0.0f;
        #pragma unroll
        for (int q = 0; q < NCHUNK; q++) xm += base[q * 64];
        s_x[tid] = xm * (1.0f / (float)NPIX);
    }
    __syncthreads();

    const float* __restrict__ w1h = head ? sw1 : mw1;
    const float* __restrict__ b1h = head ? sb1 : mb1;
    const float* __restrict__ gh  = head ? sg  : mg;
    const float* __restrict__ bth = head ? sbeta : mbeta;
    const float* __restrict__ w2h = head ? sw2 : mw2;
    const float* __restrict__ b2h = head ? sb2 : mb2;

    float hval = 0.0f, dval = 0.0f;
    {
        const float* wr = w1h + tid * 64;
        float a = b1h[tid];
        #pragma unroll
        for (int k = 0; k < 16; k++) {
            const float4 wv = *(const float4*)(wr + k * 4);
            const float4 xv = *(const float4*)(&s_x[k * 4]);
            a += wv.x * xv.x + wv.y * xv.y + wv.z * xv.z + wv.w * xv.w;
        }
        hval = a;
    }
    {
        float s = hval;
        #pragma unroll
        for (int m = 32; m >= 1; m >>= 1) s += __shfl_xor(s, m, 64);
        if (lane == 0) s_r[wid] = s;
    }
    __syncthreads();
    const float mu = (s_r[0] + s_r[1]) * (1.0f / 128.0f);
    dval = hval - mu;
    {
        float s = dval * dval;
        #pragma unroll
        for (int m = 32; m >= 1; m >>= 1) s += __shfl_xor(s, m, 64);
        if (lane == 0) s_r[wid + 2] = s;
    }
    __syncthreads();
    const float var = (s_r[2] + s_r[3]) * (1.0f / 128.0f);

    {
        const float hn = dval * (1.0f / sqrtf(var + 1e-5f)) * gh[tid] + bth[tid];
        const float sv = (hn > 0.0f)
                           ? SELU_SCALE * hn
                           : SELU_SCALE * SELU_ALPHA * (expf(hn) - 1.0f);
        s_h[tid] = sv;
    }
    __syncthreads();

    if (tid < 64) {
        const float* wr = w2h + tid * 128;
        float a = b2h[tid];
        #pragma unroll
        for (int k = 0; k < 32; k++) {
            const float4 wv = *(const float4*)(wr + k * 4);
            const float4 hv = *(const float4*)(&s_h[k * 4]);
            a += wv.x * hv.x + wv.y * hv.y + wv.z * hv.z + wv.w * hv.w;
        }
        out[(size_t)head * (size_t)n_inst * 64 + (size_t)inst * 64 + tid] = a;
    }
}

extern "C" void kernel_launch(void* const* d_in, const int* in_sizes, int n_in,
                              void* d_out, int out_size, void* d_ws, size_t ws_size,
                              hipStream_t stream) {
    const float* mask_feats  = (const float*)d_in[0];
    const float* pmain       = (const float*)d_in[1];
    const float* pside       = (const float*)d_in[2];
    const int*   im_inds     = (const int*)  d_in[3];
    const float* inst_loc    = (const float*)d_in[4];
    const float* offset_pred = (const float*)d_in[5];
    const int*   fpn_levels  = (const int*)  d_in[6];
    const float* mw1   = (const float*)d_in[7];
    const float* mb1   = (const float*)d_in[8];
    const float* mg    = (const float*)d_in[9];
    const float* mbeta = (const float*)d_in[10];
    const float* mw2   = (const float*)d_in[11];
    const float* mb2   = (const float*)d_in[12];
    const float* sw1   = (const float*)d_in[13];
    const float* sb1   = (const float*)d_in[14];
    const float* sg    = (const float*)d_in[15];
    const float* sbeta = (const float*)d_in[16];
    const float* sw2   = (const float*)d_in[17];
    const float* sb2   = (const float*)d_in[18];
    const int*   strid = (const int*)  d_in[19];
    float* out = (float*)d_out;

    const int n_inst = in_sizes[3];   // im_inds length
    float* ws_part = (float*)d_ws;    // n_inst*2*NCHUNK*64 floats ~= 2 MB

    dim3 g1(n_inst, 2, NCHUNK);
    track_head_conv<<<g1, 64, 0, stream>>>(
        mask_feats, pmain, pside, im_inds, inst_loc, offset_pred, fpn_levels,
        strid, ws_part);

    dim3 g2(n_inst, 2);
    track_head_mlp<<<g2, 128, 0, stream>>>(
        ws_part,
        mw1, mb1, mg, mbeta, mw2, mb2,
        sw1, sb1, sg, sbeta, sw2, sb2,
        out, n_inst);
}

// Round 7
// 27.629 us; speedup vs baseline: 3.1595x; 1.5594x over previous
//
#include <hip/hip_runtime.h>
#include <math.h>

// DynamicTrackHead — R7: R6 structure with a non-spilling register budget.
// K1: grid (n_inst, 2, 30), block 64 = one wave. 2 threads per pooled pixel
//     (tid>>5 = qy half), 32 pixels/block. conv0(relu,pool2x)+conv1(relu) in
//     registers; qy-pool via __shfl_xor(32); m1 staged to 1 KB LDS; conv2 with
//     one output channel per thread (broadcast LDS reads); 64 partial sums to
//     d_ws. __launch_bounds__(64,4): 128-VGPR budget -> NO SPILLS (R5/R6's
//     (64,8) forced 64-VGPR budget and spilled ~100MB of scratch traffic).
//     VGPR ~72-96 -> 4 waves/SIMD bucket; grid offers 30 waves/CU.
// K2: grid (n_inst, 2), block 128. Sum 30 partials -> mean -> MLP -> out.
// params/instance = 736 floats: w0[8][10]@0, w1[8][8]@80, w2[64][8]@144,
// b0@656, b1@664, b2@672.

#define H_IN 96
#define W_IN 160
#define HW_IN (H_IN * W_IN)
#define PW 40            // W_IN / 4
#define PH 24            // H_IN / 4
#define NPIX (PH * PW)   // 960 pooled-twice pixels
#define NCHUNK 30        // K1 blocks per (inst,head)
#define CPIX 32          // pooled pixels per K1 block
#define NPARAM 736
#define OW0 0
#define OW1 80
#define OW2 144
#define OB0 656
#define OB1 664
#define OB2 672

#define SELU_SCALE 1.0507009873554805f
#define SELU_ALPHA 1.6732632423543772f

// ---------------------------------------------------------------------------
// K1: conv tower + partial spatial sum. One wave per block.
// ---------------------------------------------------------------------------
__global__ __launch_bounds__(64, 4) void track_head_conv(
    const float* __restrict__ mask_feats,
    const float* __restrict__ pmain,
    const float* __restrict__ pside,
    const int*   __restrict__ im_inds,
    const float* __restrict__ inst_loc,
    const float* __restrict__ offset_pred,
    const int*   __restrict__ fpn_levels,
    const int*   __restrict__ stride_ptr,
    float*       __restrict__ ws_part)      // [n_inst][2][NCHUNK][64]
{
    const int inst  = blockIdx.x;
    const int head  = blockIdx.y;
    const int chunk = blockIdx.z;
    const int tid   = threadIdx.x;          // 0..63
    const int pix   = tid & 31;             // pixel within chunk
    const int qy    = tid >> 5;             // which pool-2 row half

    __shared__ __align__(16) float s_m1[CPIX][8];   // 1 KB

    const float* __restrict__ P = (head ? pside : pmain) + (size_t)inst * NPARAM;

    const int S  = stride_ptr[0];
    const int S2 = S / 2;
    float lx = inst_loc[inst * 2 + 0];
    float ly = inst_loc[inst * 2 + 1];
    if (head) {
        lx += offset_pred[inst * 2 + 0] * 128.0f;
        ly += offset_pred[inst * 2 + 1] * 128.0f;
    }
    const float inv_soi = 1.0f / (float)(64 << fpn_levels[inst]);
    const float* __restrict__ feat =
        mask_feats + (size_t)im_inds[inst] * 8 * HW_IN;

    const int p   = chunk * CPIX + pix;     // 0..959
    const int py  = p / PW;
    const int px  = p - py * PW;
    const int ix0 = px * 4;
    const int iyb = py * 4 + qy * 2;        // this thread's two input rows

    // ---- conv0 (relu folded into max), accumulate quadrant maxes ----
    float m0a[8], m0b[8];                   // pool-1 pixels (qy,qx=0/1), >=0
    #pragma unroll
    for (int o = 0; o < 8; o++) { m0a[o] = 0.0f; m0b[o] = 0.0f; }

    #pragma unroll
    for (int sy = 0; sy < 2; sy++) {
        const int iy = iyb + sy;
        const float x1 = (ly - (float)(iy * S + S2)) * inv_soi;
        const float* rowp = feat + iy * W_IN + ix0;
        const float4 f0 = *(const float4*)(rowp + 0 * HW_IN);
        const float4 f1 = *(const float4*)(rowp + 1 * HW_IN);
        const float4 f2 = *(const float4*)(rowp + 2 * HW_IN);
        const float4 f3 = *(const float4*)(rowp + 3 * HW_IN);
        const float4 f4 = *(const float4*)(rowp + 4 * HW_IN);
        const float4 f5 = *(const float4*)(rowp + 5 * HW_IN);
        const float4 f6 = *(const float4*)(rowp + 6 * HW_IN);
        const float4 f7 = *(const float4*)(rowp + 7 * HW_IN);

#define L0_PIX(JJ, COMP, M0ARR)                                                 \
        {                                                                       \
            const float x0 = (lx - (float)((ix0 + JJ) * S + S2)) * inv_soi;     \
            _Pragma("unroll")                                                   \
            for (int o = 0; o < 8; o++) {                                       \
                const float* w0r = P + OW0 + o * 10;                            \
                float a = P[OB0 + o] + w0r[0] * x0 + w0r[1] * x1                \
                        + w0r[2] * f0.COMP + w0r[3] * f1.COMP                   \
                        + w0r[4] * f2.COMP + w0r[5] * f3.COMP                   \
                        + w0r[6] * f4.COMP + w0r[7] * f5.COMP                   \
                        + w0r[8] * f6.COMP + w0r[9] * f7.COMP;                  \
                M0ARR[o] = fmaxf(M0ARR[o], a);                                  \
            }                                                                   \
        }
        L0_PIX(0, x, m0a)
        L0_PIX(1, y, m0a)
        L0_PIX(2, z, m0b)
        L0_PIX(3, w, m0b)
#undef L0_PIX
    }

    // ---- conv1 (relu) + pool over qx (local) and qy (cross-lane) ----
    float m1[8];
    #pragma unroll
    for (int o = 0; o < 8; o++) {
        float a = P[OB1 + o];
        float b = a;
        #pragma unroll
        for (int c = 0; c < 8; c++) {
            const float w = P[OW1 + o * 8 + c];
            a += w * m0a[c];
            b += w * m0b[c];
        }
        const float h = fmaxf(fmaxf(a, b), 0.0f);
        m1[o] = fmaxf(h, __shfl_xor(h, 32, 64));   // pool across qy halves
    }

    // ---- stage m1 to LDS (both halves hold identical values; benign) ----
    {
        float4* dst = (float4*)&s_m1[pix][0];
        dst[0] = make_float4(m1[0], m1[1], m1[2], m1[3]);
        dst[1] = make_float4(m1[4], m1[5], m1[6], m1[7]);
    }
    __syncthreads();

    // ---- conv2 (relu): one output channel per thread, broadcast LDS reads --
    {
        const int o = tid;                    // output channel 0..63
        const float4 wa = *(const float4*)(P + OW2 + o * 8);
        const float4 wb = *(const float4*)(P + OW2 + o * 8 + 4);
        const float  bo = P[OB2 + o];
        float accum = 0.0f;
        #pragma unroll 4
        for (int p2 = 0; p2 < CPIX; p2++) {
            const float4 va = *(const float4*)&s_m1[p2][0];   // broadcast read
            const float4 vb = *(const float4*)&s_m1[p2][4];
            float a = bo + wa.x * va.x + wa.y * va.y + wa.z * va.z + wa.w * va.w
                         + wb.x * vb.x + wb.y * vb.y + wb.z * vb.z + wb.w * vb.w;
            accum += fmaxf(a, 0.0f);
        }
        ws_part[(((size_t)inst * 2 + head) * NCHUNK + chunk) * 64 + o] = accum;
    }
}

// ---------------------------------------------------------------------------
// K2: combine partials -> mean -> MLP (fc1 -> LN -> SELU -> fc2) -> logits
// ---------------------------------------------------------------------------
__global__ __launch_bounds__(128) void track_head_mlp(
    const float* __restrict__ ws_part,
    const float* __restrict__ mw1, const float* __restrict__ mb1,
    const float* __restrict__ mg,  const float* __restrict__ mbeta,
    const float* __restrict__ mw2, const float* __restrict__ mb2,
    const float* __restrict__ sw1, const float* __restrict__ sb1,
    const float* __restrict__ sg,  const float* __restrict__ sbeta,
    const float* __restrict__ sw2, const float* __restrict__ sb2,
    float*       __restrict__ out,
    int n_inst)
{
    const int inst = blockIdx.x;
    const int head = blockIdx.y;
    const int tid  = threadIdx.x;
    const int lane = tid & 63;
    const int wid  = tid >> 6;

    __shared__ __align__(16) float s_x[64];
    __shared__ __align__(16) float s_h[128];
    __shared__ float s_r[4];

    if (tid < 64) {
        const float* base = ws_part + ((size_t)inst * 2 + head) * NCHUNK * 64 + tid;
        float xm = 0.0f;
        #pragma unroll
        for (int q = 0; q < NCHUNK; q++) xm += base[q * 64];
        s_x[tid] = xm * (1.0f / (float)NPIX);
    }
    __syncthreads();

    const float* __restrict__ w1h = head ? sw1 : mw1;
    const float* __restrict__ b1h = head ? sb1 : mb1;
    const float* __restrict__ gh  = head ? sg  : mg;
    const float* __restrict__ bth = head ? sbeta : mbeta;
    const float* __restrict__ w2h = head ? sw2 : mw2;
    const float* __restrict__ b2h = head ? sb2 : mb2;

    float hval = 0.0f, dval = 0.0f;
    {
        const float* wr = w1h + tid * 64;
        float a = b1h[tid];
        #pragma unroll
        for (int k = 0; k < 16; k++) {
            const float4 wv = *(const float4*)(wr + k * 4);
            const float4 xv = *(const float4*)(&s_x[k * 4]);
            a += wv.x * xv.x + wv.y * xv.y + wv.z * xv.z + wv.w * xv.w;
        }
        hval = a;
    }
    {
        float s = hval;
        #pragma unroll
        for (int m = 32; m >= 1; m >>= 1) s += __shfl_xor(s, m, 64);
        if (lane == 0) s_r[wid] = s;
    }
    __syncthreads();
    const float mu = (s_r[0] + s_r[1]) * (1.0f / 128.0f);
    dval = hval - mu;
    {
        float s = dval * dval;
        #pragma unroll
        for (int m = 32; m >= 1; m >>= 1) s += __shfl_xor(s, m, 64);
        if (lane == 0) s_r[wid + 2] = s;
    }
    __syncthreads();
    const float var = (s_r[2] + s_r[3]) * (1.0f / 128.0f);

    {
        const float hn = dval * (1.0f / sqrtf(var + 1e-5f)) * gh[tid] + bth[tid];
        const float sv = (hn > 0.0f)
                           ? SELU_SCALE * hn
                           : SELU_SCALE * SELU_ALPHA * (expf(hn) - 1.0f);
        s_h[tid] = sv;
    }
    __syncthreads();

    if (tid < 64) {
        const float* wr = w2h + tid * 128;
        float a = b2h[tid];
        #pragma unroll
        for (int k = 0; k < 32; k++) {
            const float4 wv = *(const float4*)(wr + k * 4);
            const float4 hv = *(const float4*)(&s_h[k * 4]);
            a += wv.x * hv.x + wv.y * hv.y + wv.z * hv.z + wv.w * hv.w;
        }
        out[(size_t)head * (size_t)n_inst * 64 + (size_t)inst * 64 + tid] = a;
    }
}

extern "C" void kernel_launch(void* const* d_in, const int* in_sizes, int n_in,
                              void* d_out, int out_size, void* d_ws, size_t ws_size,
                              hipStream_t stream) {
    const float* mask_feats  = (const float*)d_in[0];
    const float* pmain       = (const float*)d_in[1];
    const float* pside       = (const float*)d_in[2];
    const int*   im_inds     = (const int*)  d_in[3];
    const float* inst_loc    = (const float*)d_in[4];
    const float* offset_pred = (const float*)d_in[5];
    const int*   fpn_levels  = (const int*)  d_in[6];
    const float* mw1   = (const float*)d_in[7];
    const float* mb1   = (const float*)d_in[8];
    const float* mg    = (const float*)d_in[9];
    const float* mbeta = (const float*)d_in[10];
    const float* mw2   = (const float*)d_in[11];
    const float* mb2   = (const float*)d_in[12];
    const float* sw1   = (const float*)d_in[13];
    const float* sb1   = (const float*)d_in[14];
    const float* sg    = (const float*)d_in[15];
    const float* sbeta = (const float*)d_in[16];
    const float* sw2   = (const float*)d_in[17];
    const float* sb2   = (const float*)d_in[18];
    const int*   strid = (const int*)  d_in[19];
    float* out = (float*)d_out;

    const int n_inst = in_sizes[3];   // im_inds length
    float* ws_part = (float*)d_ws;    // n_inst*2*NCHUNK*64 floats ~= 2 MB

    dim3 g1(n_inst, 2, NCHUNK);
    track_head_conv<<<g1, 64, 0, stream>>>(
        mask_feats, pmain, pside, im_inds, inst_loc, offset_pred, fpn_levels,
        strid, ws_part);

    dim3 g2(n_inst, 2);
    track_head_mlp<<<g2, 128, 0, stream>>>(
        ws_part,
        mw1, mb1, mg, mbeta, mw2, mb2,
        sw1, sb1, sg, sbeta, sw2, sb2,
        out, n_inst);
}